// Round 1
// baseline (155.226 us; speedup 1.0000x reference)
//
#include <hip/hip_runtime.h>
#include <math.h>

#define FFT_N   4096
#define LOG2N   12
#define NT      256

// Radix-2 Stockham autosort FFT (DIT), one block per window.
// Stage s (m = 2^s, l = N/2/m):
//   t in [0, N/2):  j = t >> s   (t = j*m + k, so read addrs are just t, t+N/2)
//   c0 = src[t]; c1 = src[t + N/2]
//   dst[t + j*m]     = c0 + c1
//   dst[t + j*m + m] = w * (c0 - c1),  w = exp(-i*pi*j/l)
// Read addresses are linear across lanes (conflict-free); writes are
// stride<=2 patterns (2-way aliasing is free on gfx950 LDS).
__global__ __launch_bounds__(NT) void spec_fft_kernel(const float* __restrict__ x,
                                                      float* __restrict__ out) {
    __shared__ float2 buf0[FFT_N];
    __shared__ float2 buf1[FFT_N];

    const int tid = threadIdx.x;
    const size_t base = (size_t)blockIdx.x * FFT_N;
    const float4* __restrict__ xin = (const float4*)(x + base);

    // Coalesced load: 16 floats/thread as 4x float4, imag = 0
    #pragma unroll
    for (int it = 0; it < (FFT_N / 4) / NT; ++it) {
        int i = tid + it * NT;
        float4 v = xin[i];
        buf0[4 * i + 0] = make_float2(v.x, 0.0f);
        buf0[4 * i + 1] = make_float2(v.y, 0.0f);
        buf0[4 * i + 2] = make_float2(v.z, 0.0f);
        buf0[4 * i + 3] = make_float2(v.w, 0.0f);
    }
    __syncthreads();

    float2* src = buf0;
    float2* dst = buf1;

    #pragma unroll
    for (int s = 0; s < LOG2N; ++s) {
        const int m = 1 << s;
        const int l = (FFT_N / 2) >> s;
        const float astep = -(float)M_PI / (float)l;

        #pragma unroll
        for (int it = 0; it < (FFT_N / 2) / NT; ++it) {
            const int t = tid + it * NT;
            const int j = t >> s;

            float2 c0 = src[t];
            float2 c1 = src[t + FFT_N / 2];

            float sr = c0.x + c1.x;
            float si = c0.y + c1.y;
            float dr = c0.x - c1.x;
            float di = c0.y - c1.y;

            float ang = astep * (float)j;
            float wr = __cosf(ang);
            float wi = __sinf(ang);

            const int d0 = t + (t & ~(m - 1));  // t + j*m
            dst[d0]     = make_float2(sr, si);
            dst[d0 + m] = make_float2(wr * dr - wi * di, wr * di + wi * dr);
        }
        __syncthreads();
        float2* tmp = src; src = dst; dst = tmp;
    }

    // |F(k)|^2, coalesced store
    float* __restrict__ o = out + base;
    #pragma unroll
    for (int it = 0; it < FFT_N / NT; ++it) {
        int i = tid + it * NT;
        float2 c = src[i];
        o[i] = c.x * c.x + c.y * c.y;
    }
}

extern "C" void kernel_launch(void* const* d_in, const int* in_sizes, int n_in,
                              void* d_out, int out_size, void* d_ws, size_t ws_size,
                              hipStream_t stream) {
    const float* x = (const float*)d_in[0];
    float* out = (float*)d_out;
    const int B = in_sizes[0] / FFT_N;  // 8192
    spec_fft_kernel<<<B, NT, 0, stream>>>(x, out);
}

// Round 2
// 49.120 us; speedup vs baseline: 3.1601x; 3.1601x over previous
//
#include <hip/hip_runtime.h>
#include <math.h>

#define FFT_N   4096
#define NT      256
// Padded LDS index: +1 float2 per 16 → every stage's strided access sits at
// the 4-cycle wave64 b64 floor (no above-floor bank conflicts).
#define PHYS(i) ((i) + ((i) >> 4))
#define LDS_SZ  (FFT_N + FFT_N / 16)

__device__ __forceinline__ float2 cadd(float2 a, float2 b) { return make_float2(a.x + b.x, a.y + b.y); }
__device__ __forceinline__ float2 csub(float2 a, float2 b) { return make_float2(a.x - b.x, a.y - b.y); }
__device__ __forceinline__ float2 cmul(float2 a, float2 b) { return make_float2(a.x * b.x - a.y * b.y, a.x * b.y + a.y * b.x); }

// In-place 4-point DFT (ω4 = -i). X0=a+b+c+d; X1=(a-c)-i(b-d); X2=(a+c)-(b+d); X3=(a-c)+i(b-d)
__device__ __forceinline__ void dft4(float2& a, float2& b, float2& c, float2& d) {
    float2 t0 = cadd(a, c);
    float2 t1 = csub(a, c);
    float2 t2 = cadd(b, d);
    float2 t3 = make_float2(b.y - d.y, d.x - b.x);  // -i*(b-d)
    a = cadd(t0, t2);
    b = cadd(t1, t3);
    c = csub(t0, t2);
    d = csub(t1, t3);
}

// 16-point DFT in registers via radix-4 x radix-4.
// Input v[r] = c_r. Output: DFT16[q1 + 4*q2] lands in v[4*q1 + q2]
// (digit-reversed register order — caller maps q -> reg = ((q&3)<<2)|(q>>2)).
__device__ __forceinline__ void dft16(float2 v[16]) {
    // step 1: DFT4 over r2 groups {r1, r1+4, r1+8, r1+12}; B[r1][q1] -> v[r1+4*q1]
    #pragma unroll
    for (int r1 = 0; r1 < 4; ++r1)
        dft4(v[r1], v[r1 + 4], v[r1 + 8], v[r1 + 12]);

    // step 2: v[r1 + 4*q1] *= w16^(q1*r1), w16^k = (cos(pi k/8), -sin(pi k/8))
    const float C1 = 0.92387953251128675613f;  // cos(pi/8)
    const float S1 = 0.38268343236508977173f;  // sin(pi/8)
    const float R2 = 0.70710678118654752440f;  // sqrt(2)/2
    v[5]  = cmul(v[5],  make_float2( C1, -S1));   // k=1
    v[9]  = cmul(v[9],  make_float2( R2, -R2));   // k=2
    v[13] = cmul(v[13], make_float2( S1, -C1));   // k=3
    v[6]  = cmul(v[6],  make_float2( R2, -R2));   // k=2
    v[10] = make_float2(v[10].y, -v[10].x);       // k=4: * -i
    v[14] = cmul(v[14], make_float2(-R2, -R2));   // k=6
    v[7]  = cmul(v[7],  make_float2( S1, -C1));   // k=3
    v[11] = cmul(v[11], make_float2(-R2, -R2));   // k=6
    v[15] = cmul(v[15], make_float2(-C1,  S1));   // k=9 = -w16^1
    // step 3: for each q1, DFT4 over r1 {4q1..4q1+3}; result[q2] -> v[4*q1 + q2]
    #pragma unroll
    for (int q1 = 0; q1 < 4; ++q1)
        dft4(v[4 * q1], v[4 * q1 + 1], v[4 * q1 + 2], v[4 * q1 + 3]);
}

// One radix-16 Stockham stage, M = 16^s. Reads all 16 pts/thread, barrier,
// DFT16 in regs, inter-stage twiddle, write back (single buffer), barrier.
template <int M>
__device__ __forceinline__ void fft_stage(float2* buf, int tid) {
    const int j = tid / M;
    const int k = tid % M;
    float2 v[16];
    #pragma unroll
    for (int r = 0; r < 16; ++r) v[r] = buf[PHYS(tid + 256 * r)];
    __syncthreads();

    dft16(v);

    const float base = (float)j * (-6.28318530717958647692f * (float)M / (float)FFT_N);
    const int obase = j * 16 * M + k;
    #pragma unroll
    for (int q = 0; q < 16; ++q) {
        const int reg = ((q & 3) << 2) | (q >> 2);
        float2 d = v[reg];
        if (M != 256 && q != 0) {  // last stage: j==0 -> all twiddles are 1
            float sn, cs;
            __sincosf(base * (float)q, &sn, &cs);
            d = make_float2(d.x * cs - d.y * sn, d.x * sn + d.y * cs);
        }
        buf[PHYS(obase + q * M)] = d;
    }
    __syncthreads();
}

// One block per PAIR of windows: z = x1 + i*x2, one 4096-pt complex FFT,
// unpack |F1|^2, |F2|^2 via conjugate symmetry.
__global__ __launch_bounds__(NT) void spec_fft_kernel(const float* __restrict__ x,
                                                      float* __restrict__ out) {
    __shared__ float2 buf[LDS_SZ];
    const int tid = threadIdx.x;
    const size_t base = (size_t)blockIdx.x * (2 * FFT_N);
    const float4* __restrict__ x1 = (const float4*)(x + base);
    const float4* __restrict__ x2 = (const float4*)(x + base + FFT_N);

    #pragma unroll
    for (int it = 0; it < 4; ++it) {
        int idx = tid + 256 * it;  // float4 index within row
        float4 a = x1[idx];
        float4 b = x2[idx];
        buf[PHYS(4 * idx + 0)] = make_float2(a.x, b.x);
        buf[PHYS(4 * idx + 1)] = make_float2(a.y, b.y);
        buf[PHYS(4 * idx + 2)] = make_float2(a.z, b.z);
        buf[PHYS(4 * idx + 3)] = make_float2(a.w, b.w);
    }
    __syncthreads();

    fft_stage<1>(buf, tid);
    fft_stage<16>(buf, tid);
    fft_stage<256>(buf, tid);

    // Epilogue: F1(k) = (Z(k)+conj(Z(N-k)))/2, F2(k) = (Z(k)-conj(Z(N-k)))/(2i)
    float* __restrict__ o1 = out + base;
    float* __restrict__ o2 = out + base + FFT_N;
    #pragma unroll
    for (int it = 0; it < 4; ++it) {
        int idx = tid + 256 * it;
        float4 r1, r2;
        #pragma unroll
        for (int c = 0; c < 4; ++c) {
            int k = 4 * idx + c;
            float2 zk = buf[PHYS(k)];
            float2 zn = buf[PHYS((FFT_N - k) & (FFT_N - 1))];
            float e1r = zk.x + zn.x, e1i = zk.y - zn.y;   // 2*F1
            float e2r = zk.x - zn.x, e2i = zk.y + zn.y;   // 2i*F2 (same magnitude as 2*F2)
            (&r1.x)[c] = 0.25f * (e1r * e1r + e1i * e1i);
            (&r2.x)[c] = 0.25f * (e2r * e2r + e2i * e2i);
        }
        ((float4*)o1)[idx] = r1;
        ((float4*)o2)[idx] = r2;
    }
}

extern "C" void kernel_launch(void* const* d_in, const int* in_sizes, int n_in,
                              void* d_out, int out_size, void* d_ws, size_t ws_size,
                              hipStream_t stream) {
    const float* x = (const float*)d_in[0];
    float* out = (float*)d_out;
    const int B = in_sizes[0] / FFT_N;  // 8192
    spec_fft_kernel<<<B / 2, NT, 0, stream>>>(x, out);
}